// Round 6
// baseline (207.611 us; speedup 1.0000x reference)
//
#include <hip/hip_runtime.h>
#include <cstdint>
#include <cstddef>

// KAN layer: out[b,j] = sum_{i,k} basis_k(tanh x[b,i]) * C[j,i,k]
// basis is 2-sparse (adjacent slots lo, lo+1); pad to 16 slots/i.
// R17: ATOMIC-EPILOGUE ATTACK on R16's (correct, verified) granule pipeline.
// R13/R15/R16 all pinned at 122-125us across every schedule lever => the
// shared limiter is elsewhere. WRITE_SIZE = exactly 64 MB (= out * KSPL2=8
// atomic RMWs all reaching HBM) and the old grid put the 8 same-tile
// writers on 8 DIFFERENT XCDs (linear%8 = i-split) -> cross-XCD atomic
// ping-pong storm at every block tail. R17: KSPL2 4 (halves atomic bytes),
// grid flipped to (m=64,1,s=4) so linear%8 = m%8: all 4 i-splits of an out
// tile reduce on the SAME XCD's L2; x rows L2-shared likewise. B2 reads
// spill to L3 (was L2) - covered by ring-4 prefetch distance.
// Pipeline per granule (2 i, K=32) unchanged from R16: {4x ds_read_b128 A |
// stage g+2 (2 chunks) | expand g+1 | s_waitcnt vmcnt(3) lgkmcnt(0) |
// s_barrier | sched_barrier | setprio(1) 16 MFMA setprio(0)}.

typedef _Float16 half2_v __attribute__((ext_vector_type(2)));
typedef __fp16  fp16x2  __attribute__((ext_vector_type(2)));
typedef _Float16 f16x8 __attribute__((ext_vector_type(8)));
typedef float f32x4 __attribute__((ext_vector_type(4)));

__device__ __forceinline__ half2_v u32_as_h2(uint32_t u) {
  union { uint32_t u; half2_v h; } c; c.u = u; return c.h;
}
__device__ __forceinline__ uint32_t h2_as_u32(half2_v h) {
  union { uint32_t u; half2_v h; } c; c.h = h; return c.u;
}
__device__ __forceinline__ half2_v cvt_pk_h2(float a, float b) {
  union { fp16x2 f; half2_v h; } c;
  c.f = __builtin_amdgcn_cvt_pkrtz(a, b);
  return c.h;
}
__device__ __forceinline__ float dot2f(half2_v a, half2_v b, float c) {
#if __has_builtin(__builtin_amdgcn_fdot2)
  return __builtin_amdgcn_fdot2(a, b, c, false);
#else
  return c + (float)a[0] * (float)b[0] + (float)a[1] * (float)b[1];
#endif
}
__device__ __forceinline__ uint16_t f16_bits(float v) {
  union { _Float16 h; uint16_t u; } c; c.h = (_Float16)v; return c.u;
}

__device__ __forceinline__ float fast_tanhf(float v) {
  const float e = __expf(2.0f * v);
  return 1.0f - 2.0f / (e + 1.0f);
}

// ---- basis-weight computation (analytic uniform knots; verified R10) ----
#define KSTEP 0.13333333333333333f
#define KINV  7.49999943750004f      // 1/(2/15 + 1e-8)
__device__ __forceinline__ void kan_weights(float xin, float& w0, float& w1, int& lo) {
  float xc = fast_tanhf(xin);
  xc = fminf(fmaxf(xc, -1.0f), 1.0f);
  int m = (int)((xc + 1.0f) * 7.5f);   // interval index; basis continuity makes +-1 ULP safe
  m = min(max(m, 0), 14);
  const float k0 = fmaf((float)m, KSTEP, -1.0f);
  const float up = (xc - k0) * KINV;
  const float dn = (k0 + KSTEP - xc) * KINV;
  // m==0: up on slot 0 | 1<=m<=11: dn on m-1, up on m | m==12: dn on 11 | m>=13: zero
  w0 = (m == 0) ? up : ((m <= 12) ? dn : 0.0f);
  w1 = (m >= 1 && m <= 11) ? up : 0.0f;
  lo = min(max(m - 1, 0), 11);
}

__device__ __forceinline__ void load_lds16(const void* g, void* l) {
  __builtin_amdgcn_global_load_lds((const __attribute__((address_space(1))) void*)g,
                                   (__attribute__((address_space(3))) void*)l, 16, 0, 0);
}

// ================= fast path =================
#define GMM 8192
#define GNN 256
#define KI  16                 // padded slots per i
#define GK2 (1024 * KI)        // 16384
#define KSPL2 4
#define IPER (1024 / KSPL2)    // 256 i per split
#define BM2 128
#define BN2 256
#define NGRAN 128              // granules per block (2 i each)
#define NBODY 32               // unrolled 4-granule bodies

// prep_B2: f16 B2[j][i*16+s], s=0..11 from coef, 12..15 zero (slot12 unused).
// Also zeroes out[] (replaces the separate memset dispatch).
__global__ __launch_bounds__(256)
void kan_prep_B2(const float* __restrict__ coef, uint32_t* __restrict__ B2,
                 float4* __restrict__ outz) {
  const int tid = blockIdx.x * 256 + threadIdx.x;   // flat (j,i), 262144
  const float* cp = coef + (size_t)tid * 13;
  uint32_t w[8];
#pragma unroll
  for (int q = 0; q < 6; ++q) w[q] = h2_as_u32(cvt_pk_h2(cp[2 * q], cp[2 * q + 1]));
  w[6] = 0u; w[7] = 0u;
  uint4* p = (uint4*)(B2 + (size_t)tid * 8);
  p[0] = make_uint4(w[0], w[1], w[2], w[3]);
  p[1] = make_uint4(w[4], w[5], w[6], w[7]);
  // out: 8192*256 f32 = 524288 float4; 262144 threads x 2
  const float4 z = make_float4(0.f, 0.f, 0.f, 0.f);
  outz[tid] = z;
  outz[tid + 262144] = z;
}

__global__ __launch_bounds__(512, 4)
void kan_gemm11(const float* __restrict__ x, const _Float16* __restrict__ B2,
                float* __restrict__ out) {
  // Bs: ring-4 granule buffers [256 j][2 i x 16 slots = 64B], chunk-swizzled
  //     (LDS chunk c' holds logical chunk c'^ (row&3)).
  // As: ring-2 granule buffers [2 i][128 rows][32B], 16B-half swap on (row>>2)&1.
  __shared__ __align__(16) char Bs[4][16384];
  __shared__ __align__(16) char As[2][8192];
  char* BsP = (char*)Bs;
  char* AsP = (char*)As;

  const int t    = threadIdx.x;
  const int lane = t & 63;
  const int wv   = t >> 6;          // 0..7
  const int wm   = (wv & 1) * 64;   // wave m-offset (of 128)
  const int wn   = (wv >> 1) * 64;  // wave n-offset (of 256)
  const int fr   = lane & 15;
  const int fq   = lane >> 4;
  const int m0   = blockIdx.x * BM2;   // R17: m on grid-x
  const int i00  = blockIdx.z * IPER;  // R17: i-split on grid-z -> XCD = m%8

  // ds_read bases (all slot/frag offsets fold into 16-bit immediates)
  const int fr_swz = (((wm >> 2) + (fr >> 2)) & 1) * 16;
  const int a_base = (wm + fr) * 32 + (((fq & 1) * 16) ^ fr_swz) + (fq >> 1) * 4096;
  const int b_base = (wn + fr) * 64 + ((fq ^ (fr & 3)) * 16);

  f32x4 acc[4][4];
#pragma unroll
  for (int a = 0; a < 4; ++a)
#pragma unroll
    for (int b = 0; b < 4; ++b) acc[a][b] = (f32x4){0.f, 0.f, 0.f, 0.f};

  // B staging: granule tile 16 KB = 1024 x 16B chunks; thread t owns chunks
  // {t, 512+t}: row = n>>2, c = n&3, global chunk = c ^ (row&3).
  const int srow0 = t >> 2, sc0 = t & 3;
  const int srow1 = 128 + (t >> 2);
  const _Float16* sp0 = B2 + (size_t)srow0 * GK2 + (size_t)i00 * KI
                        + ((sc0 ^ (srow0 & 3)) * 8);
  const _Float16* sp1 = B2 + (size_t)srow1 * GK2 + (size_t)i00 * KI
                        + ((sc0 ^ (srow1 & 3)) * 8);
  // x / expand: thread owns (row = (t>>1)&127, parity = t&1, i_off = (t>>8)&1);
  // its x element for window w: x[m0+row][i00 + 4w + 2*parity + i_off].
  const int xrow   = (t >> 1) & 127;
  const int parity = t & 1;
  const int i_off  = (t >> 8) & 1;
  const float* xptr = x + (size_t)(m0 + xrow) * 1024 + i00 + 2 * parity + i_off;
  const int exp_off = (i_off * 128 + xrow) * 32;
  const int p_swz   = ((xrow >> 2) & 1) * 16;

  auto expand1 = [&](int aw, float xv) {
    float w0, w1; int lo;
    kan_weights(xv, w0, w1, lo);
    const uint32_t wp  = (uint32_t)f16_bits(w0) | ((uint32_t)f16_bits(w1) << 16);
    const uint32_t wlo = (lo & 1) ? (wp << 16) : wp;
    const uint32_t whi = (lo & 1) ? (wp >> 16) : 0u;
    const int w = lo >> 1;
    char* rb = AsP + aw + exp_off;
    *(uint4*)(rb + p_swz)        = make_uint4(0u, 0u, 0u, 0u);
    *(uint4*)(rb + (p_swz ^ 16)) = make_uint4(0u, 0u, 0u, 0u);
    *(uint32_t*)(rb + (((w + 1) * 4) ^ p_swz)) = whi;
    *(uint32_t*)(rb + ((w * 4) ^ p_swz))       = wlo;
  };

  float xa, xb, xn1, xn2;

  // ---- prologue: x(w0), x(w1); stage g0->slot0, g1->slot1; expand g0 ----
  xa = xptr[0];
  xb = xptr[4];
  load_lds16(sp0, BsP + 0 + t * 16);
  load_lds16(sp1, BsP + 0 + 8192 + t * 16);
  sp0 += 32; sp1 += 32;
  load_lds16(sp0, BsP + 16384 + t * 16);
  load_lds16(sp1, BsP + 16384 + 8192 + t * 16);
  sp0 += 32; sp1 += 32;
  if (parity == 0) expand1(0, xa);       // g0 (even) -> As[0]
  // need g0 landed; newer vmem: g1's 2 chunks -> vmcnt(2)
  asm volatile("s_waitcnt vmcnt(2) lgkmcnt(0)" ::: "memory");
  __builtin_amdgcn_s_barrier();
  __builtin_amdgcn_sched_barrier(0);

#define MFMA16(RS)                                                            \
  __builtin_amdgcn_s_setprio(1);                                              \
  _Pragma("unroll")                                                           \
  for (int ni = 0; ni < 4; ++ni) {                                            \
    const f16x8 bf = *(const f16x8*)(BsP + (RS) + b_base + ni * 1024);        \
    acc[0][ni] = __builtin_amdgcn_mfma_f32_16x16x32_f16(af0, bf, acc[0][ni], 0, 0, 0); \
    acc[1][ni] = __builtin_amdgcn_mfma_f32_16x16x32_f16(af1, bf, acc[1][ni], 0, 0, 0); \
    acc[2][ni] = __builtin_amdgcn_mfma_f32_16x16x32_f16(af2, bf, acc[2][ni], 0, 0, 0); \
    acc[3][ni] = __builtin_amdgcn_mfma_f32_16x16x32_f16(af3, bf, acc[3][ni], 0, 0, 0); \
  }                                                                           \
  __builtin_amdgcn_s_setprio(0);

// Granule body at compile-time position P (0..3) within the 4-granule body.
// Reads Bs slot P / As[P&1]; stages granule g+2 -> slot (P+2)&3; expands
// granule g+1 (parity (P+1)&1) -> As[(P+1)&1]; then counted-wait + barrier
// + 16 MFMA. ADV: pointer advance (clamped at tail so dummy stages re-read
// granule NGRAN-1 in-bounds; dummy targets are dead ring slots -- the
// barrier in the intervening granule orders them after the last reads).
#define GRAN(P, XV, ADV, XLOAD)                                               \
  {                                                                           \
    f16x8 af0 = *(const f16x8*)(AsP + ((P) & 1) * 8192 + a_base);             \
    f16x8 af1 = *(const f16x8*)(AsP + ((P) & 1) * 8192 + a_base + 512);       \
    f16x8 af2 = *(const f16x8*)(AsP + ((P) & 1) * 8192 + a_base + 1024);      \
    f16x8 af3 = *(const f16x8*)(AsP + ((P) & 1) * 8192 + a_base + 1536);      \
    load_lds16(sp0, BsP + (((P) + 2) & 3) * 16384 + t * 16);                  \
    load_lds16(sp1, BsP + (((P) + 2) & 3) * 16384 + 8192 + t * 16);           \
    sp0 += (ADV); sp1 += (ADV);                                               \
    XLOAD                                                                     \
    if (parity == (((P) + 1) & 1)) expand1((((P) + 1) & 1) * 8192, XV);       \
    asm volatile("s_waitcnt vmcnt(3) lgkmcnt(0)" ::: "memory");               \
    __builtin_amdgcn_s_barrier();                                             \
    __builtin_amdgcn_sched_barrier(0);                                        \
    MFMA16((P) * 16384)                                                       \
  }

  for (int itw = 0; itw < NBODY; ++itw) {
    const int g0 = 4 * itw;
    const int adv0 = (g0 + 3 <= NGRAN - 1) ? 32 : 0;
    const int adv1 = (g0 + 4 <= NGRAN - 1) ? 32 : 0;
    const int adv2 = (g0 + 5 <= NGRAN - 1) ? 32 : 0;
    const int adv3 = (g0 + 6 <= NGRAN - 1) ? 32 : 0;
    int xw1 = 2 * itw + 2; if (xw1 > IPER / 4 - 1) xw1 = IPER / 4 - 1;
    int xw2 = 2 * itw + 3; if (xw2 > IPER / 4 - 1) xw2 = IPER / 4 - 1;

    GRAN(0, xa, adv0, { xn1 = xptr[4 * xw1]; })
    GRAN(1, xb, adv1, { })
    GRAN(2, xb, adv2, { xn2 = xptr[4 * xw2]; })
    GRAN(3, xn1, adv3, { })

    xa = xn1; xb = xn2;
  }
#undef GRAN
#undef MFMA16

#pragma unroll
  for (int q = 0; q < 4; ++q) {
    const int gr = m0 + wm + q * 16 + fq * 4;
#pragma unroll
    for (int ni = 0; ni < 4; ++ni) {
      const int gc = wn + ni * 16 + fr;
#pragma unroll
      for (int r = 0; r < 4; ++r)
        atomicAdd(&out[(size_t)(gr + r) * GNN + gc], acc[q][ni][r]);
    }
  }
}

// ================= fallback: direct dot2 path (no workspace) =================
#define TI 8
#define BT 256
#define JT 32
#define ISPL 2
#define IRANGE (1024 / ISPL)

__global__ __launch_bounds__(256)
void kan_dot2(const float* __restrict__ x, const float* __restrict__ coef,
              float* __restrict__ out) {
  __shared__ uint32_t Plds[TI * 12 * JT];
  const int t    = threadIdx.x;
  const int b    = blockIdx.x * BT + t;
  const int j0   = blockIdx.y * JT;
  const int cbeg = blockIdx.z * (IRANGE / TI);

  float acc[JT];
#pragma unroll
  for (int q = 0; q < JT; ++q) acc[q] = 0.0f;

  const int s_jj   = t & 31;
  const int s_iloc = t >> 5;

  for (int c = cbeg; c < cbeg + IRANGE / TI; ++c) {
    const int i0 = c * TI;
    __syncthreads();
    {
      const float* cp0 = coef + ((size_t)(j0 + s_jj) * 1024 + (i0 + s_iloc)) * 13;
      float cv[13];
#pragma unroll
      for (int s = 0; s < 13; ++s) cv[s] = cp0[s];
#pragma unroll
      for (int r = 0; r < 12; ++r) {
        half2_v h; h[0] = (_Float16)cv[r]; h[1] = (_Float16)cv[r + 1];
        const int slot = ((s_jj >> 2) + r) & 7;
        Plds[(s_iloc * 12 + r) * 32 + slot * 4 + (s_jj & 3)] = h2_as_u32(h);
      }
    }
    uint32_t wr[TI]; int lor[TI];
    {
      const float* xr = x + (size_t)b * 1024 + i0;
      const float4 xa = *(const float4*)(xr);
      const float4 xb = *(const float4*)(xr + 4);
      const float xv[TI] = {xa.x, xa.y, xa.z, xa.w, xb.x, xb.y, xb.z, xb.w};
#pragma unroll
      for (int q = 0; q < TI; ++q) {
        float w0, w1; int lo;
        kan_weights(xv[q], w0, w1, lo);
        wr[q] = (uint32_t)f16_bits(w0) | ((uint32_t)f16_bits(w1) << 16);
        lor[q] = lo;
      }
    }
    __syncthreads();

    const uint4* P4 = (const uint4*)Plds;
#pragma unroll
    for (int ii = 0; ii < TI; ++ii) {
      const half2_v hw = u32_as_h2(wr[ii]);
      const int lo = lor[ii];
      const int base = (ii * 12 + lo) * 8;
#pragma unroll
      for (int g = 0; g < 8; ++g) {
        const uint4 v = P4[base + ((g + lo) & 7)];
        acc[4 * g + 0] = dot2f(hw, u32_as_h2(v.x), acc[4 * g + 0]);
        acc[4 * g + 1] = dot2f(hw, u32_as_h2(v.y), acc[4 * g + 1]);
        acc[4 * g + 2] = dot2f(hw, u32_as_h2(v.z), acc[4 * g + 2]);
        acc[4 * g + 3] = dot2f(hw, u32_as_h2(v.w), acc[4 * g + 3]);
      }
    }
  }

  float* orow = out + (size_t)b * 256 + j0;
#pragma unroll
  for (int q = 0; q < JT; ++q) atomicAdd(orow + q, acc[q]);
}

extern "C" void kernel_launch(void* const* d_in, const int* in_sizes, int n_in,
                              void* d_out, int out_size, void* d_ws, size_t ws_size,
                              hipStream_t stream) {
  const float* x     = (const float*)d_in[0];
  const float* coef  = (const float*)d_in[1];
  float* out = (float*)d_out;

  const size_t nB2 = (size_t)GNN * GK2;                  // f16 elements (8.4 MB)
  if (ws_size >= nB2 * 2) {
    _Float16* B2 = (_Float16*)d_ws;
    // prep_B2 also zeroes out[] (memset folded in; same-stream ordering).
    kan_prep_B2<<<(int)((size_t)GNN * 1024 / 256), 256, 0, stream>>>(
        coef, (uint32_t*)B2, (float4*)out);
    // R17 grid: (m-tiles, 1, i-splits): linear = m + 64*s -> XCD = m%8.
    // All 4 i-splits of one out-tile reduce on the SAME XCD; x rows
    // L2-shared by its 4 readers. 256 blocks = 1/CU.
    dim3 grid(GMM / BM2, 1, KSPL2);                      // (64, 1, 4)
    kan_gemm11<<<grid, 512, 0, stream>>>(x, B2, out);
  } else {
    (void)hipMemsetAsync(out, 0, (size_t)out_size * sizeof(float), stream);
    dim3 grid(8192 / BT, 256 / JT, ISPL);
    kan_dot2<<<grid, 256, 0, stream>>>(x, coef, out);
  }
}

// Round 7
// 196.370 us; speedup vs baseline: 1.0572x; 1.0572x over previous
//
#include <hip/hip_runtime.h>
#include <cstdint>
#include <cstddef>

// KAN layer: out[b,j] = sum_{i,k} basis_k(tanh x[b,i]) * C[j,i,k]
// basis is 2-sparse (adjacent slots lo, lo+1), support slots 0..11 ONLY.
// R18: KI 16 -> 12 (remove the always-zero pad slots 12..15). R13-R17
// exonerated schedule/occupancy/atomics (all ~122us); the shared 25% tax
// was the padded K. Now: B2[j][i*12+s] (6.3 MB), K-step = 32 slots = 64B,
// super-granule = 8 i = 3 K-steps (LCM(12,32)=96). A-panel row = 192B data
// + 16B pad (stride 208 = 13 words x 16: odd multiplier -> frag reads AND
// zero-writes hit the 8/bank floor, no swizzle needed). Expand clamps the
// word-6 spill (lo=11 => w1==0 analytically). Pipeline = R16's verified
// granule engine (ring-4 Bs, stage distance 2, vmcnt(3) counted, barrier
// safety proof carries over). Grid = R16's (i-split -> XCD, FETCH-optimal).

typedef _Float16 half2_v __attribute__((ext_vector_type(2)));
typedef __fp16  fp16x2  __attribute__((ext_vector_type(2)));
typedef _Float16 f16x8 __attribute__((ext_vector_type(8)));
typedef float f32x4 __attribute__((ext_vector_type(4)));

__device__ __forceinline__ half2_v u32_as_h2(uint32_t u) {
  union { uint32_t u; half2_v h; } c; c.u = u; return c.h;
}
__device__ __forceinline__ uint32_t h2_as_u32(half2_v h) {
  union { uint32_t u; half2_v h; } c; c.h = h; return c.u;
}
__device__ __forceinline__ half2_v cvt_pk_h2(float a, float b) {
  union { fp16x2 f; half2_v h; } c;
  c.f = __builtin_amdgcn_cvt_pkrtz(a, b);
  return c.h;
}
__device__ __forceinline__ float dot2f(half2_v a, half2_v b, float c) {
#if __has_builtin(__builtin_amdgcn_fdot2)
  return __builtin_amdgcn_fdot2(a, b, c, false);
#else
  return c + (float)a[0] * (float)b[0] + (float)a[1] * (float)b[1];
#endif
}
__device__ __forceinline__ uint16_t f16_bits(float v) {
  union { _Float16 h; uint16_t u; } c; c.h = (_Float16)v; return c.u;
}

__device__ __forceinline__ float fast_tanhf(float v) {
  const float e = __expf(2.0f * v);
  return 1.0f - 2.0f / (e + 1.0f);
}

// ---- basis-weight computation (analytic uniform knots; verified R10) ----
#define KSTEP 0.13333333333333333f
#define KINV  7.49999943750004f      // 1/(2/15 + 1e-8)
__device__ __forceinline__ void kan_weights(float xin, float& w0, float& w1, int& lo) {
  float xc = fast_tanhf(xin);
  xc = fminf(fmaxf(xc, -1.0f), 1.0f);
  int m = (int)((xc + 1.0f) * 7.5f);   // interval index; basis continuity makes +-1 ULP safe
  m = min(max(m, 0), 14);
  const float k0 = fmaf((float)m, KSTEP, -1.0f);
  const float up = (xc - k0) * KINV;
  const float dn = (k0 + KSTEP - xc) * KINV;
  // m==0: up on slot 0 | 1<=m<=11: dn on m-1, up on m | m==12: dn on 11 | m>=13: zero
  w0 = (m == 0) ? up : ((m <= 12) ? dn : 0.0f);
  w1 = (m >= 1 && m <= 11) ? up : 0.0f;
  lo = min(max(m - 1, 0), 11);
}

__device__ __forceinline__ void load_lds16(const void* g, void* l) {
  __builtin_amdgcn_global_load_lds((const __attribute__((address_space(1))) void*)g,
                                   (__attribute__((address_space(3))) void*)l, 16, 0, 0);
}

// ================= fast path =================
#define GMM 8192
#define GNN 256
#define KI  12                 // slots per i (true support)
#define GK2 (1024 * KI)        // 12288 f16 per B2 row
#define KSPL2 8
#define IPER (1024 / KSPL2)    // 128 i per split
#define BM2 128
#define BN2 256
#define NSG 16                 // super-granules per block (8 i each)
#define NSTEP 48               // K-steps per block (3 per sg)
#define AS_STRIDE 208          // 192 B data + 16 B pad (13 words: odd -> bank spread)
#define AS_SG (128 * AS_STRIDE)

// prep_B2: f16 B2[j][i*12+s], s=0..11 from coef (slot 12 of coef is always
// multiplied by zero basis). Also zeroes out[] (memset folded in).
__global__ __launch_bounds__(256)
void kan_prep_B2(const float* __restrict__ coef, uint32_t* __restrict__ B2,
                 float4* __restrict__ outz) {
  const int tid = blockIdx.x * 256 + threadIdx.x;   // flat (j,i), 262144
  const float* cp = coef + (size_t)tid * 13;
  uint32_t w[6];
#pragma unroll
  for (int q = 0; q < 6; ++q) w[q] = h2_as_u32(cvt_pk_h2(cp[2 * q], cp[2 * q + 1]));
  uint2* p = (uint2*)(B2 + (size_t)tid * 6);        // 24 B per (j,i), 8B aligned
  p[0] = make_uint2(w[0], w[1]);
  p[1] = make_uint2(w[2], w[3]);
  p[2] = make_uint2(w[4], w[5]);
  // out: 8192*256 f32 = 524288 float4; 262144 threads x 2
  const float4 z = make_float4(0.f, 0.f, 0.f, 0.f);
  outz[tid] = z;
  outz[tid + 262144] = z;
}

__global__ __launch_bounds__(512, 2)
void kan_gemm12(const float* __restrict__ x, const _Float16* __restrict__ B2,
                float* __restrict__ out) {
  // Bs: ring-4 K-step buffers [256 j][64 B], chunk-swizzled (LDS chunk c
  //     holds global chunk c ^ (row&3)).
  // As: ring-2 super-granule buffers [128 rows][8 i x 24 B + 16 pad].
  __shared__ __align__(16) char Bs[4][16384];
  __shared__ __align__(16) char As[2][AS_SG];
  char* BsP = (char*)Bs;
  char* AsP = (char*)As;

  const int t    = threadIdx.x;
  const int lane = t & 63;
  const int wv   = t >> 6;          // 0..7
  const int wm   = (wv & 1) * 64;   // wave m-offset (of 128)
  const int wn   = (wv >> 1) * 64;  // wave n-offset (of 256)
  const int fr   = lane & 15;
  const int fq   = lane >> 4;
  const int m0   = blockIdx.z * BM2;   // R16 grid: m on z
  const int i00  = blockIdx.x * IPER;  // i-split on x -> XCD = i-split

  // frag bases: A slice for K-step ks at a_base + ks*64 (+ q*16*AS_STRIDE);
  // B slice at b_base + ni*1024 within the step's 16 KB slot.
  const int a_base = (wm + fr) * AS_STRIDE + fq * 16;
  const int b_base = (wn + fr) * 64 + ((fq ^ (fr & 3)) * 16);

  f32x4 acc[4][4];
#pragma unroll
  for (int a = 0; a < 4; ++a)
#pragma unroll
    for (int b = 0; b < 4; ++b) acc[a][b] = (f32x4){0.f, 0.f, 0.f, 0.f};

  // B staging: per K-step tile [256 j][64 B] = 1024 x 16B chunks; thread t
  // owns {t, 512+t}: row = n>>2, LDS chunk sc holds global chunk sc^(row&3).
  const int srow0 = t >> 2, sc0 = t & 3;
  const int srow1 = 128 + (t >> 2);
  const _Float16* sp0 = B2 + (size_t)srow0 * GK2 + (size_t)i00 * KI
                        + ((sc0 ^ (srow0 & 3)) * 8);
  const _Float16* sp1 = B2 + (size_t)srow1 * GK2 + (size_t)i00 * KI
                        + ((sc0 ^ (srow1 & 3)) * 8);
  // per K-step advance: 32 f16 = 64 B.

  // expand mapping: thread t -> (row = t&127, i_loc = t>>7 in 0..3); handles
  // i_loc and i_loc+4 of each 8-i super-granule. i_loc is wave-uniform.
  const int xrow  = t & 127;
  const int i_loc = t >> 7;
  const float* xptr = x + (size_t)(m0 + xrow) * 1024 + i00 + i_loc;

  auto expand1 = [&](int dst, float xv, int il) {
    float w0, w1; int lo;
    kan_weights(xv, w0, w1, lo);
    const uint32_t wp  = (uint32_t)f16_bits(w0) | ((uint32_t)f16_bits(w1) << 16);
    const uint32_t wlo = (lo & 1) ? (wp << 16) : wp;
    const uint32_t whi = (lo & 1) ? (wp >> 16) : 0u;
    const int w   = lo >> 1;                       // word 0..5
    const int wn1 = (w + 1 > 5) ? 5 : (w + 1);     // clamp: lo=11 => w1==0
    char* rb = AsP + dst + xrow * AS_STRIDE + il * 24;
    if ((il & 1) == 0) {                           // wave-uniform branch
      *(uint4*)(rb)      = make_uint4(0u, 0u, 0u, 0u);
      *(uint2*)(rb + 16) = make_uint2(0u, 0u);
    } else {
      *(uint2*)(rb)      = make_uint2(0u, 0u);
      *(uint4*)(rb + 8)  = make_uint4(0u, 0u, 0u, 0u);
    }
    *(uint32_t*)(rb + wn1 * 4) = whi;              // order: whi then wlo
    *(uint32_t*)(rb + w * 4)   = wlo;              // (same-word clamp: wlo wins)
  };

  float cxa, cxb, nxa = 0.f, nxb = 0.f;

  // ---- prologue: x(sg0) -> expand As[0]; stage step0->slot0, step1->slot1 ----
  {
    const float exa = xptr[0];
    const float exb = xptr[4];
    load_lds16(sp0, BsP + t * 16);
    load_lds16(sp1, BsP + 8192 + t * 16);
    sp0 += 32; sp1 += 32;
    load_lds16(sp0, BsP + 16384 + t * 16);
    load_lds16(sp1, BsP + 16384 + 8192 + t * 16);
    sp0 += 32; sp1 += 32;
    expand1(0, exa, i_loc);
    expand1(0, exb, i_loc + 4);
    cxa = xptr[8];                    // x(sg1)
    cxb = xptr[12];
  }
  // robust to x-load interleave: all-but-2-newest forces slot0 landed.
  asm volatile("s_waitcnt vmcnt(2) lgkmcnt(0)" ::: "memory");
  __builtin_amdgcn_s_barrier();
  __builtin_amdgcn_sched_barrier(0);

// Phase = one K-step (global step g = 12B + 3U + PH). Reads As[U&1] slice
// PH, Bs slot (3U+PH)&3; stages step g+2 -> slot (3U+PH+2)&3; expands
// sg+1 into As[(U+1)&1] at PH 0/1; counted wait vmcnt(3) (stage(g) has >=4
// newer vmem ops incl. x prefetches -> forced complete); barrier; 16 MFMA.
#define GRANP(U, PH, XPF)                                                     \
  {                                                                           \
    const int g = 12 * B + 3 * (U) + (PH);                                    \
    const char* Asrc = AsP + ((U) & 1) * AS_SG;                               \
    f16x8 af0 = *(const f16x8*)(Asrc + a_base + (PH) * 64);                   \
    f16x8 af1 = *(const f16x8*)(Asrc + a_base + (PH) * 64 + 16 * AS_STRIDE);  \
    f16x8 af2 = *(const f16x8*)(Asrc + a_base + (PH) * 64 + 32 * AS_STRIDE);  \
    f16x8 af3 = *(const f16x8*)(Asrc + a_base + (PH) * 64 + 48 * AS_STRIDE);  \
    load_lds16(sp0, BsP + ((3 * (U) + (PH) + 2) & 3) * 16384 + t * 16);       \
    load_lds16(sp1, BsP + ((3 * (U) + (PH) + 2) & 3) * 16384 + 8192 + t * 16);\
    { const int adv = (g + 3 <= NSTEP - 1) ? 32 : 0; sp0 += adv; sp1 += adv; }\
    XPF                                                                       \
    if ((PH) == 0 && (4 * B + (U)) < NSG - 1)                                 \
      expand1((((U) + 1) & 1) * AS_SG, cxa, i_loc);                           \
    if ((PH) == 1 && (4 * B + (U)) < NSG - 1)                                 \
      expand1((((U) + 1) & 1) * AS_SG, cxb, i_loc + 4);                       \
    asm volatile("s_waitcnt vmcnt(3) lgkmcnt(0)" ::: "memory");               \
    __builtin_amdgcn_s_barrier();                                             \
    __builtin_amdgcn_sched_barrier(0);                                        \
    __builtin_amdgcn_s_setprio(1);                                            \
    _Pragma("unroll")                                                         \
    for (int ni = 0; ni < 4; ++ni) {                                          \
      const f16x8 bf = *(const f16x8*)(BsP + ((3 * (U) + (PH)) & 3) * 16384   \
                                       + b_base + ni * 1024);                 \
      acc[0][ni] = __builtin_amdgcn_mfma_f32_16x16x32_f16(af0, bf, acc[0][ni], 0, 0, 0); \
      acc[1][ni] = __builtin_amdgcn_mfma_f32_16x16x32_f16(af1, bf, acc[1][ni], 0, 0, 0); \
      acc[2][ni] = __builtin_amdgcn_mfma_f32_16x16x32_f16(af2, bf, acc[2][ni], 0, 0, 0); \
      acc[3][ni] = __builtin_amdgcn_mfma_f32_16x16x32_f16(af3, bf, acc[3][ni], 0, 0, 0); \
    }                                                                         \
    __builtin_amdgcn_s_setprio(0);                                            \
  }

#define SGBODY(U)                                                             \
  {                                                                           \
    const int sgp = 4 * B + (U) + 2;                                          \
    const int sgn = (sgp < NSG) ? sgp : (NSG - 1);                            \
    GRANP(U, 0, { nxa = xptr[8 * sgn]; })                                     \
    GRANP(U, 1, { })                                                          \
    GRANP(U, 2, { nxb = xptr[8 * sgn + 4]; })                                 \
    cxa = nxa; cxb = nxb;                                                     \
  }

  for (int B = 0; B < 4; ++B) {
    SGBODY(0)
    SGBODY(1)
    SGBODY(2)
    SGBODY(3)
  }
#undef SGBODY
#undef GRANP

#pragma unroll
  for (int q = 0; q < 4; ++q) {
    const int gr = m0 + wm + q * 16 + fq * 4;
#pragma unroll
    for (int ni = 0; ni < 4; ++ni) {
      const int gc = wn + ni * 16 + fr;
#pragma unroll
      for (int r = 0; r < 4; ++r)
        atomicAdd(&out[(size_t)(gr + r) * GNN + gc], acc[q][ni][r]);
    }
  }
}

// ================= fallback: direct dot2 path (no workspace) =================
#define TI 8
#define BT 256
#define JT 32
#define ISPL 2
#define IRANGE (1024 / ISPL)

__global__ __launch_bounds__(256)
void kan_dot2(const float* __restrict__ x, const float* __restrict__ coef,
              float* __restrict__ out) {
  __shared__ uint32_t Plds[TI * 12 * JT];
  const int t    = threadIdx.x;
  const int b    = blockIdx.x * BT + t;
  const int j0   = blockIdx.y * JT;
  const int cbeg = blockIdx.z * (IRANGE / TI);

  float acc[JT];
#pragma unroll
  for (int q = 0; q < JT; ++q) acc[q] = 0.0f;

  const int s_jj   = t & 31;
  const int s_iloc = t >> 5;

  for (int c = cbeg; c < cbeg + IRANGE / TI; ++c) {
    const int i0 = c * TI;
    __syncthreads();
    {
      const float* cp0 = coef + ((size_t)(j0 + s_jj) * 1024 + (i0 + s_iloc)) * 13;
      float cv[13];
#pragma unroll
      for (int s = 0; s < 13; ++s) cv[s] = cp0[s];
#pragma unroll
      for (int r = 0; r < 12; ++r) {
        half2_v h; h[0] = (_Float16)cv[r]; h[1] = (_Float16)cv[r + 1];
        const int slot = ((s_jj >> 2) + r) & 7;
        Plds[(s_iloc * 12 + r) * 32 + slot * 4 + (s_jj & 3)] = h2_as_u32(h);
      }
    }
    uint32_t wr[TI]; int lor[TI];
    {
      const float* xr = x + (size_t)b * 1024 + i0;
      const float4 xa = *(const float4*)(xr);
      const float4 xb = *(const float4*)(xr + 4);
      const float xv[TI] = {xa.x, xa.y, xa.z, xa.w, xb.x, xb.y, xb.z, xb.w};
#pragma unroll
      for (int q = 0; q < TI; ++q) {
        float w0, w1; int lo;
        kan_weights(xv[q], w0, w1, lo);
        wr[q] = (uint32_t)f16_bits(w0) | ((uint32_t)f16_bits(w1) << 16);
        lor[q] = lo;
      }
    }
    __syncthreads();

    const uint4* P4 = (const uint4*)Plds;
#pragma unroll
    for (int ii = 0; ii < TI; ++ii) {
      const half2_v hw = u32_as_h2(wr[ii]);
      const int lo = lor[ii];
      const int base = (ii * 12 + lo) * 8;
#pragma unroll
      for (int g = 0; g < 8; ++g) {
        const uint4 v = P4[base + ((g + lo) & 7)];
        acc[4 * g + 0] = dot2f(hw, u32_as_h2(v.x), acc[4 * g + 0]);
        acc[4 * g + 1] = dot2f(hw, u32_as_h2(v.y), acc[4 * g + 1]);
        acc[4 * g + 2] = dot2f(hw, u32_as_h2(v.z), acc[4 * g + 2]);
        acc[4 * g + 3] = dot2f(hw, u32_as_h2(v.w), acc[4 * g + 3]);
      }
    }
  }

  float* orow = out + (size_t)b * 256 + j0;
#pragma unroll
  for (int q = 0; q < JT; ++q) atomicAdd(orow + q, acc[q]);
}

extern "C" void kernel_launch(void* const* d_in, const int* in_sizes, int n_in,
                              void* d_out, int out_size, void* d_ws, size_t ws_size,
                              hipStream_t stream) {
  const float* x     = (const float*)d_in[0];
  const float* coef  = (const float*)d_in[1];
  float* out = (float*)d_out;

  const size_t nB2 = (size_t)GNN * GK2;                  // f16 elements (6.3 MB)
  if (ws_size >= nB2 * 2) {
    _Float16* B2 = (_Float16*)d_ws;
    // prep_B2 also zeroes out[] (memset folded in; same-stream ordering).
    kan_prep_B2<<<(int)((size_t)GNN * 1024 / 256), 256, 0, stream>>>(
        coef, (uint32_t*)B2, (float4*)out);
    // R16 grid: (i-splits, 1, m-tiles) z-major -> XCD = i-split; each XCD's
    // B2 window (787 KB) is L2-resident.
    dim3 grid(KSPL2, 1, GMM / BM2);                      // (8, 1, 64)
    kan_gemm12<<<grid, 512, 0, stream>>>(x, B2, out);
  } else {
    (void)hipMemsetAsync(out, 0, (size_t)out_size * sizeof(float), stream);
    dim3 grid(8192 / BT, 256 / JT, ISPL);
    kan_dot2<<<grid, 256, 0, stream>>>(x, coef, out);
  }
}

// Round 8
// 187.508 us; speedup vs baseline: 1.1072x; 1.0473x over previous
//
#include <hip/hip_runtime.h>
#include <cstdint>
#include <cstddef>

// KAN layer: out[b,j] = sum_{i,k} basis_k(tanh x[b,i]) * C[j,i,k]
// basis is 2-sparse (adjacent slots lo, lo+1), support slots 0..11.
// R19: BYTE-BUDGET ATTACK. R11-R18 counters fit dur ~= (FETCH+WRITE)/~700GB/s
// across six different kernels; bytes are dominated by atomic WRITE = out *
// KSPL2 (device atomics resolve past L2 -> fabric round-trip each; R17
// proved same-XCD placement doesn't help). So: KSPL2 8->2 (atomic bytes
// 64->16 MB), and when ws_size permits, NO atomics at all: plain-store
// per-split partials in d_ws + tiny reduce kernel. Grid (s=2,1,m=128):
// linear = s+2m -> XCD parity = s -> each XCD's 3.1 MB B2 half L2-resident.
// Engine = R18's verified ring-4 Bs / ring-2 As granule pipeline (stage
// distance 2, counted vmcnt(3), barrier-skew safety proof carries over).
// BM2=64: 8 waves = 2m x 4n, wave tile 32x64, acc[2][4]; expand = 1
// item/thread/sg (64 rows x 8 i = 512).

typedef _Float16 half2_v __attribute__((ext_vector_type(2)));
typedef __fp16  fp16x2  __attribute__((ext_vector_type(2)));
typedef _Float16 f16x8 __attribute__((ext_vector_type(8)));
typedef float f32x4 __attribute__((ext_vector_type(4)));

__device__ __forceinline__ half2_v u32_as_h2(uint32_t u) {
  union { uint32_t u; half2_v h; } c; c.u = u; return c.h;
}
__device__ __forceinline__ uint32_t h2_as_u32(half2_v h) {
  union { uint32_t u; half2_v h; } c; c.h = h; return c.u;
}
__device__ __forceinline__ half2_v cvt_pk_h2(float a, float b) {
  union { fp16x2 f; half2_v h; } c;
  c.f = __builtin_amdgcn_cvt_pkrtz(a, b);
  return c.h;
}
__device__ __forceinline__ float dot2f(half2_v a, half2_v b, float c) {
#if __has_builtin(__builtin_amdgcn_fdot2)
  return __builtin_amdgcn_fdot2(a, b, c, false);
#else
  return c + (float)a[0] * (float)b[0] + (float)a[1] * (float)b[1];
#endif
}
__device__ __forceinline__ uint16_t f16_bits(float v) {
  union { _Float16 h; uint16_t u; } c; c.h = (_Float16)v; return c.u;
}

__device__ __forceinline__ float fast_tanhf(float v) {
  const float e = __expf(2.0f * v);
  return 1.0f - 2.0f / (e + 1.0f);
}

// ---- basis-weight computation (analytic uniform knots; verified R10) ----
#define KSTEP 0.13333333333333333f
#define KINV  7.49999943750004f      // 1/(2/15 + 1e-8)
__device__ __forceinline__ void kan_weights(float xin, float& w0, float& w1, int& lo) {
  float xc = fast_tanhf(xin);
  xc = fminf(fmaxf(xc, -1.0f), 1.0f);
  int m = (int)((xc + 1.0f) * 7.5f);   // interval index; basis continuity makes +-1 ULP safe
  m = min(max(m, 0), 14);
  const float k0 = fmaf((float)m, KSTEP, -1.0f);
  const float up = (xc - k0) * KINV;
  const float dn = (k0 + KSTEP - xc) * KINV;
  // m==0: up on slot 0 | 1<=m<=11: dn on m-1, up on m | m==12: dn on 11 | m>=13: zero
  w0 = (m == 0) ? up : ((m <= 12) ? dn : 0.0f);
  w1 = (m >= 1 && m <= 11) ? up : 0.0f;
  lo = min(max(m - 1, 0), 11);
}

__device__ __forceinline__ void load_lds16(const void* g, void* l) {
  __builtin_amdgcn_global_load_lds((const __attribute__((address_space(1))) void*)g,
                                   (__attribute__((address_space(3))) void*)l, 16, 0, 0);
}

// ================= fast path =================
#define GMM 8192
#define GNN 256
#define KI  12                 // slots per i (true support)
#define GK2 (1024 * KI)        // 12288 f16 per B2 row
#define KSPL2 2
#define IPER (1024 / KSPL2)    // 512 i per split
#define BM2 64
#define BN2 256
#define NSG 64                 // super-granules per block (8 i each)
#define NSTEP 192              // K-steps per block (3 per sg)
#define AS_STRIDE 208          // 192 B data + 16 B pad (13 words: odd -> bank spread)
#define AS_SG (64 * AS_STRIDE) // 13312 B
#define OUT_ELEMS (8192 * 256)

// prep_B2: f16 B2[j][i*12+s], s=0..11 from coef. Optionally zeroes out[]
// (only needed for the atomic epilogue path).
__global__ __launch_bounds__(256)
void kan_prep_B2(const float* __restrict__ coef, uint32_t* __restrict__ B2,
                 float4* __restrict__ outz, int zero_out) {
  const int tid = blockIdx.x * 256 + threadIdx.x;   // flat (j,i), 262144
  const float* cp = coef + (size_t)tid * 13;
  uint32_t w[6];
#pragma unroll
  for (int q = 0; q < 6; ++q) w[q] = h2_as_u32(cvt_pk_h2(cp[2 * q], cp[2 * q + 1]));
  uint2* p = (uint2*)(B2 + (size_t)tid * 6);        // 24 B per (j,i), 8B aligned
  p[0] = make_uint2(w[0], w[1]);
  p[1] = make_uint2(w[2], w[3]);
  p[2] = make_uint2(w[4], w[5]);
  if (zero_out) {
    const float4 z = make_float4(0.f, 0.f, 0.f, 0.f);
    outz[tid] = z;
    outz[tid + 262144] = z;
  }
}

// reduce: out = part[0] + part[1] (partial-sum path)
__global__ __launch_bounds__(256)
void kan_reduce2(const float4* __restrict__ part, float4* __restrict__ out) {
  const int i = blockIdx.x * 256 + threadIdx.x;     // 524288 float4
  out[i] = make_float4(part[i].x + part[i + OUT_ELEMS / 4].x,
                       part[i].y + part[i + OUT_ELEMS / 4].y,
                       part[i].z + part[i + OUT_ELEMS / 4].z,
                       part[i].w + part[i + OUT_ELEMS / 4].w);
}

__global__ __launch_bounds__(512, 2)
void kan_gemm13(const float* __restrict__ x, const _Float16* __restrict__ B2,
                float* __restrict__ out, float* __restrict__ part, int mode) {
  // Bs: ring-4 K-step buffers [256 j][64 B], chunk-swizzled (LDS chunk c
  //     holds global chunk c ^ (row&3)).
  // As: ring-2 super-granule buffers [64 rows][8 i x 24 B + 16 pad].
  __shared__ __align__(16) char Bs[4][16384];
  __shared__ __align__(16) char As[2][AS_SG];
  char* BsP = (char*)Bs;
  char* AsP = (char*)As;

  const int t    = threadIdx.x;
  const int lane = t & 63;
  const int wv   = t >> 6;          // 0..7
  const int wm   = (wv & 1) * 32;   // wave m-offset (of 64)
  const int wn   = (wv >> 1) * 64;  // wave n-offset (of 256)
  const int fr   = lane & 15;
  const int fq   = lane >> 4;
  const int m0   = blockIdx.z * BM2;   // m on z
  const int i00  = blockIdx.x * IPER;  // i-split on x; linear = s+2m -> XCD parity = s

  // frag bases
  const int a_base = (wm + fr) * AS_STRIDE + fq * 16;
  const int b_base = (wn + fr) * 64 + ((fq ^ (fr & 3)) * 16);

  f32x4 acc[2][4];
#pragma unroll
  for (int a = 0; a < 2; ++a)
#pragma unroll
    for (int b = 0; b < 4; ++b) acc[a][b] = (f32x4){0.f, 0.f, 0.f, 0.f};

  // B staging: per K-step tile [256 j][64 B] = 1024 x 16B chunks; thread t
  // owns {t, 512+t}: row = n>>2, LDS chunk sc holds global chunk sc^(row&3).
  const int srow0 = t >> 2, sc0 = t & 3;
  const int srow1 = 128 + (t >> 2);
  const _Float16* sp0 = B2 + (size_t)srow0 * GK2 + (size_t)i00 * KI
                        + ((sc0 ^ (srow0 & 3)) * 8);
  const _Float16* sp1 = B2 + (size_t)srow1 * GK2 + (size_t)i00 * KI
                        + ((sc0 ^ (srow1 & 3)) * 8);
  // per K-step advance: 32 f16 = 64 B.

  // expand mapping: thread t -> (row = t&63, i_loc = t>>6 in 0..7) — one
  // item per sg. i_loc == wave id (wave-uniform).
  const int xrow  = t & 63;
  const int i_loc = t >> 6;
  const float* xptr = x + (size_t)(m0 + xrow) * 1024 + i00 + i_loc;
  const int exp_off = xrow * AS_STRIDE + i_loc * 24;

  auto expand1 = [&](int dst, float xv) {
    float w0, w1; int lo;
    kan_weights(xv, w0, w1, lo);
    const uint32_t wp  = (uint32_t)f16_bits(w0) | ((uint32_t)f16_bits(w1) << 16);
    const uint32_t wlo = (lo & 1) ? (wp << 16) : wp;
    const uint32_t whi = (lo & 1) ? (wp >> 16) : 0u;
    const int w   = lo >> 1;                       // word 0..5
    const int wn1 = (w + 1 > 5) ? 5 : (w + 1);     // clamp: lo=11 => w1==0
    char* rb = AsP + dst + exp_off;
    if ((i_loc & 1) == 0) {                        // wave-uniform branch
      *(uint4*)(rb)      = make_uint4(0u, 0u, 0u, 0u);
      *(uint2*)(rb + 16) = make_uint2(0u, 0u);
    } else {
      *(uint2*)(rb)      = make_uint2(0u, 0u);
      *(uint4*)(rb + 8)  = make_uint4(0u, 0u, 0u, 0u);
    }
    *(uint32_t*)(rb + wn1 * 4) = whi;              // order: whi then wlo
    *(uint32_t*)(rb + w * 4)   = wlo;              // (same-word clamp: wlo wins)
  };

  float cx, nx = 0.f;

  // ---- prologue: expand sg0 -> As[0]; stage step0->slot0, step1->slot1 ----
  {
    const float ex = xptr[0];
    load_lds16(sp0, BsP + t * 16);
    load_lds16(sp1, BsP + 8192 + t * 16);
    sp0 += 32; sp1 += 32;
    load_lds16(sp0, BsP + 16384 + t * 16);
    load_lds16(sp1, BsP + 16384 + 8192 + t * 16);
    sp0 += 32; sp1 += 32;
    expand1(0, ex);
    cx = xptr[8];                     // x(sg1)
  }
  // vmcnt(2): of the 5 possibly-outstanding vmem ops, allow only the 2
  // newest -> step0's pair complete regardless of compiler interleave.
  asm volatile("s_waitcnt vmcnt(2) lgkmcnt(0)" ::: "memory");
  __builtin_amdgcn_s_barrier();
  __builtin_amdgcn_sched_barrier(0);

// Phase = one K-step (global g = 12B + 3U + PH, slot (3U+PH)&3). Reads
// As[U&1] slice PH; stages step g+2 -> slot (3U+PH+2)&3; expands sg+1 into
// As[(U+1)&1] at PH0; counted wait vmcnt(3) (the 3 newest = stage(g+2) x2
// + at most 1 x prefetch -> stage(g+1) forced complete); barrier; 8 MFMA.
#define GRANP(U, PH, XPF)                                                     \
  {                                                                           \
    const int g = 12 * B + 3 * (U) + (PH);                                    \
    const char* Asrc = AsP + ((U) & 1) * AS_SG;                               \
    f16x8 af0 = *(const f16x8*)(Asrc + a_base + (PH) * 64);                   \
    f16x8 af1 = *(const f16x8*)(Asrc + a_base + (PH) * 64 + 16 * AS_STRIDE);  \
    load_lds16(sp0, BsP + ((3 * (U) + (PH) + 2) & 3) * 16384 + t * 16);       \
    load_lds16(sp1, BsP + ((3 * (U) + (PH) + 2) & 3) * 16384 + 8192 + t * 16);\
    { const int adv = (g + 3 <= NSTEP - 1) ? 32 : 0; sp0 += adv; sp1 += adv; }\
    XPF                                                                       \
    if ((PH) == 0 && (4 * B + (U)) < NSG - 1)                                 \
      expand1((((U) + 1) & 1) * AS_SG, cx);                                   \
    asm volatile("s_waitcnt vmcnt(3) lgkmcnt(0)" ::: "memory");               \
    __builtin_amdgcn_s_barrier();                                             \
    __builtin_amdgcn_sched_barrier(0);                                        \
    __builtin_amdgcn_s_setprio(1);                                            \
    _Pragma("unroll")                                                         \
    for (int ni = 0; ni < 4; ++ni) {                                          \
      const f16x8 bf = *(const f16x8*)(BsP + ((3 * (U) + (PH)) & 3) * 16384   \
                                       + b_base + ni * 1024);                 \
      acc[0][ni] = __builtin_amdgcn_mfma_f32_16x16x32_f16(af0, bf, acc[0][ni], 0, 0, 0); \
      acc[1][ni] = __builtin_amdgcn_mfma_f32_16x16x32_f16(af1, bf, acc[1][ni], 0, 0, 0); \
    }                                                                         \
    __builtin_amdgcn_s_setprio(0);                                            \
  }

#define SGBODY(U)                                                             \
  {                                                                           \
    const int sgp = 4 * B + (U) + 2;                                          \
    const int sgn = (sgp < NSG) ? sgp : (NSG - 1);                            \
    GRANP(U, 0, { })                                                          \
    GRANP(U, 1, { nx = xptr[8 * sgn]; })                                      \
    GRANP(U, 2, { })                                                          \
    cx = nx;                                                                  \
  }

  for (int B = 0; B < 16; ++B) {
    SGBODY(0)
    SGBODY(1)
    SGBODY(2)
    SGBODY(3)
  }
#undef SGBODY
#undef GRANP

  if (mode) {
    // partial-sum path: plain stores into part[s][b][j] (no atomics)
    float* pb = part + (size_t)blockIdx.x * OUT_ELEMS;
#pragma unroll
    for (int q = 0; q < 2; ++q) {
      const int gr = m0 + wm + q * 16 + fq * 4;
#pragma unroll
      for (int ni = 0; ni < 4; ++ni) {
        const int gc = wn + ni * 16 + fr;
#pragma unroll
        for (int r = 0; r < 4; ++r)
          pb[(size_t)(gr + r) * GNN + gc] = acc[q][ni][r];
      }
    }
  } else {
#pragma unroll
    for (int q = 0; q < 2; ++q) {
      const int gr = m0 + wm + q * 16 + fq * 4;
#pragma unroll
      for (int ni = 0; ni < 4; ++ni) {
        const int gc = wn + ni * 16 + fr;
#pragma unroll
        for (int r = 0; r < 4; ++r)
          atomicAdd(&out[(size_t)(gr + r) * GNN + gc], acc[q][ni][r]);
      }
    }
  }
}

// ================= fallback: direct dot2 path (no workspace) =================
#define TI 8
#define BT 256
#define JT 32
#define ISPL 2
#define IRANGE (1024 / ISPL)

__global__ __launch_bounds__(256)
void kan_dot2(const float* __restrict__ x, const float* __restrict__ coef,
              float* __restrict__ out) {
  __shared__ uint32_t Plds[TI * 12 * JT];
  const int t    = threadIdx.x;
  const int b    = blockIdx.x * BT + t;
  const int j0   = blockIdx.y * JT;
  const int cbeg = blockIdx.z * (IRANGE / TI);

  float acc[JT];
#pragma unroll
  for (int q = 0; q < JT; ++q) acc[q] = 0.0f;

  const int s_jj   = t & 31;
  const int s_iloc = t >> 5;

  for (int c = cbeg; c < cbeg + IRANGE / TI; ++c) {
    const int i0 = c * TI;
    __syncthreads();
    {
      const float* cp0 = coef + ((size_t)(j0 + s_jj) * 1024 + (i0 + s_iloc)) * 13;
      float cv[13];
#pragma unroll
      for (int s = 0; s < 13; ++s) cv[s] = cp0[s];
#pragma unroll
      for (int r = 0; r < 12; ++r) {
        half2_v h; h[0] = (_Float16)cv[r]; h[1] = (_Float16)cv[r + 1];
        const int slot = ((s_jj >> 2) + r) & 7;
        Plds[(s_iloc * 12 + r) * 32 + slot * 4 + (s_jj & 3)] = h2_as_u32(h);
      }
    }
    uint32_t wr[TI]; int lor[TI];
    {
      const float* xr = x + (size_t)b * 1024 + i0;
      const float4 xa = *(const float4*)(xr);
      const float4 xb = *(const float4*)(xr + 4);
      const float xv[TI] = {xa.x, xa.y, xa.z, xa.w, xb.x, xb.y, xb.z, xb.w};
#pragma unroll
      for (int q = 0; q < TI; ++q) {
        float w0, w1; int lo;
        kan_weights(xv[q], w0, w1, lo);
        wr[q] = (uint32_t)f16_bits(w0) | ((uint32_t)f16_bits(w1) << 16);
        lor[q] = lo;
      }
    }
    __syncthreads();

    const uint4* P4 = (const uint4*)Plds;
#pragma unroll
    for (int ii = 0; ii < TI; ++ii) {
      const half2_v hw = u32_as_h2(wr[ii]);
      const int lo = lor[ii];
      const int base = (ii * 12 + lo) * 8;
#pragma unroll
      for (int g = 0; g < 8; ++g) {
        const uint4 v = P4[base + ((g + lo) & 7)];
        acc[4 * g + 0] = dot2f(hw, u32_as_h2(v.x), acc[4 * g + 0]);
        acc[4 * g + 1] = dot2f(hw, u32_as_h2(v.y), acc[4 * g + 1]);
        acc[4 * g + 2] = dot2f(hw, u32_as_h2(v.z), acc[4 * g + 2]);
        acc[4 * g + 3] = dot2f(hw, u32_as_h2(v.w), acc[4 * g + 3]);
      }
    }
  }

  float* orow = out + (size_t)b * 256 + j0;
#pragma unroll
  for (int q = 0; q < JT; ++q) atomicAdd(orow + q, acc[q]);
}

extern "C" void kernel_launch(void* const* d_in, const int* in_sizes, int n_in,
                              void* d_out, int out_size, void* d_ws, size_t ws_size,
                              hipStream_t stream) {
  const float* x     = (const float*)d_in[0];
  const float* coef  = (const float*)d_in[1];
  float* out = (float*)d_out;

  const size_t b2_bytes   = (size_t)GNN * GK2 * 2;           // 6.29 MB
  const size_t part_off   = b2_bytes;                        // 16-B aligned
  const size_t part_bytes = (size_t)KSPL2 * OUT_ELEMS * 4;   // 16.8 MB

  if (ws_size >= part_off + part_bytes) {
    // no-atomic path: per-split partials + reduce
    _Float16* B2 = (_Float16*)d_ws;
    float* part  = (float*)((char*)d_ws + part_off);
    kan_prep_B2<<<1024, 256, 0, stream>>>(coef, (uint32_t*)B2, (float4*)out, 0);
    dim3 grid(KSPL2, 1, GMM / BM2);                          // (2, 1, 128)
    kan_gemm13<<<grid, 512, 0, stream>>>(x, B2, out, part, 1);
    kan_reduce2<<<OUT_ELEMS / 4 / 256, 256, 0, stream>>>((const float4*)part,
                                                         (float4*)out);
  } else if (ws_size >= b2_bytes) {
    // atomic path (16 MB of atomics, 4x less than R18)
    _Float16* B2 = (_Float16*)d_ws;
    kan_prep_B2<<<1024, 256, 0, stream>>>(coef, (uint32_t*)B2, (float4*)out, 1);
    dim3 grid(KSPL2, 1, GMM / BM2);
    kan_gemm13<<<grid, 512, 0, stream>>>(x, B2, out, nullptr, 0);
  } else {
    (void)hipMemsetAsync(out, 0, (size_t)out_size * sizeof(float), stream);
    dim3 grid(8192 / BT, 256 / JT, ISPL);
    kan_dot2<<<grid, 256, 0, stream>>>(x, coef, out);
  }
}